// Round 19
// baseline (952.361 us; speedup 1.0000x reference)
//
#include <hip/hip_runtime.h>
#include <hip/hip_bf16.h>

typedef __attribute__((ext_vector_type(4))) float f32x4;
typedef __attribute__((ext_vector_type(8))) short short8;
using uint = unsigned int;
using ushort = unsigned short;

#define DEV __device__ __forceinline__

DEV ushort f2bf(float f) {
  uint u = __builtin_bit_cast(uint, f);
  u = (u + 0x7fffu + ((u >> 16) & 1u)) >> 16;
  return (ushort)u;
}
DEV float bf2f(ushort b) { uint u = ((uint)b) << 16; return __builtin_bit_cast(float, u); }
DEV uint pack2(float lo, float hi) { return (uint)f2bf(lo) | ((uint)f2bf(hi) << 16); }

// async global->LDS, 16B per lane. LDS dest = wave-uniform base + lane*16.
DEV void gll16(const ushort* g, ushort* l) {
  __builtin_amdgcn_global_load_lds((const __attribute__((address_space(1))) void*)g,
                                   (__attribute__((address_space(3))) void*)l, 16, 0, 0);
}

#define MFMA_BF16 __builtin_amdgcn_mfma_f32_16x16x32_bf16

// ---------------------------------------------------------------------------
// fp32 -> bf16 cast (weights), 8 elems/thread
// ---------------------------------------------------------------------------
__global__ __launch_bounds__(256) void cast_bf16_k(const float* __restrict__ src, ushort* __restrict__ dst) {
  size_t i = ((size_t)blockIdx.x * 256 + threadIdx.x) * 8;
  float4 a = *(const float4*)(src + i);
  float4 b = *(const float4*)(src + i + 4);
  uint4 u;
  u.x = pack2(a.x, a.y); u.y = pack2(a.z, a.w);
  u.z = pack2(b.x, b.y); u.w = pack2(b.z, b.w);
  *(uint4*)(dst + i) = u;
}

// ---------------------------------------------------------------------------
// RoPE cos/sin table: [2048][128], sections [48,40,40] (pairs 24/20/20)
// ---------------------------------------------------------------------------
__global__ __launch_bounds__(256) void rope_table_k(float* __restrict__ cost, float* __restrict__ sint) {
  int idx = blockIdx.x * 256 + threadIdx.x;   // 0..262143
  int s = idx >> 7, d = idx & 127;
  const float LN1E6 = 13.815510557964274f;
  float inv;
  if (d < 48)      { int i = d % 24;        inv = expf((float)i * (-2.f / 48.f) * LN1E6); }
  else if (d < 88) { int i = (d - 48) % 20; inv = expf((float)i * (-2.f / 40.f) * LN1E6); }
  else             { int i = (d - 88) % 20; inv = expf((float)i * (-2.f / 40.f) * LN1E6); }
  float ang = (float)s * inv;
  cost[idx] = cosf(ang);
  sint[idx] = sinf(ang);
}

// ---------------------------------------------------------------------------
// Row RMSNorm: in fp32 [R][2048] * w[2048] -> out bf16
// ---------------------------------------------------------------------------
__global__ __launch_bounds__(256) void rmsnorm_k(const float* __restrict__ in, const float* __restrict__ w,
                                                 ushort* __restrict__ out) {
  int row = blockIdx.x;
  const float* x = in + (size_t)row * 2048;
  int base = threadIdx.x * 8;
  float4 a = *(const float4*)(x + base);
  float4 b = *(const float4*)(x + base + 4);
  float ss = a.x*a.x + a.y*a.y + a.z*a.z + a.w*a.w + b.x*b.x + b.y*b.y + b.z*b.z + b.w*b.w;
#pragma unroll
  for (int msk = 1; msk <= 32; msk <<= 1) ss += __shfl_xor(ss, msk);
  __shared__ float red[4];
  if ((threadIdx.x & 63) == 0) red[threadIdx.x >> 6] = ss;
  __syncthreads();
  float tot = red[0] + red[1] + red[2] + red[3];
  float r = rsqrtf(tot * (1.f / 2048.f) + 1e-6f);
  float4 wa = *(const float4*)(w + base);
  float4 wb = *(const float4*)(w + base + 4);
  uint4 u;
  u.x = pack2(a.x * r * wa.x, a.y * r * wa.y);
  u.y = pack2(a.z * r * wa.z, a.w * r * wa.w);
  u.z = pack2(b.x * r * wb.x, b.y * r * wb.y);
  u.w = pack2(b.z * r * wb.z, b.w * r * wb.w);
  *(uint4*)(out + (size_t)row * 2048 + base) = u;
}

// ---------------------------------------------------------------------------
// GEMM v12 — r16 K-loop (128x128, BK=64, 4 waves, single 32 KB buffer,
// syncthreads pair, coalesced chunk-XOR-swizzled staging, 0 conflicts)
// + COLUMN-SYNCHRONIZED XCD MAPPING: xcd = id&7 (HW round-robin), j = id>>3;
//   m0 = (xcd*(gy/8) + j/gx)*128, n0 = (j%gx)*128.
// At each dispatch step all 8 XCDs read the SAME B column panel (one HBM
// fetch, L3-broadcast to 8 L2s) while streaming their private A rows
// (L2-resident). B (<=33.5MB) stays L3-resident between m-row sweeps ->
// fetch approaches compulsory ~50-90MB (was 180MB = B refetched 4x).
// Requires gy%8==0 (all grids use gy=32). Works for all K.
// MODE 0: C bf16.  MODE 1: C fp32 = acc + resid.  MODE 2: C = silu(C)*acc.
// ---------------------------------------------------------------------------
template <int MODE>
__global__ __launch_bounds__(256, 4) void gemm_bb(
    const ushort* __restrict__ A, int lda,
    const ushort* __restrict__ B, int ldb,
    ushort* __restrict__ Cb, float* __restrict__ Cf,
    const float* __restrict__ resid, int ldc, int K) {
  __shared__ ushort smem[2 * 128 * 64];  // As | Bs, 32 KB
  ushort* As = smem;
  ushort* Bs = smem + 128 * 64;

  int tid = threadIdx.x;
  int w = tid >> 6, lane = tid & 63, g = lane >> 4, c = lane & 15;
  int wr = w >> 1, wc = w & 1;

  // column-synchronized XCD mapping
  int gx = gridDim.x;
  int id = blockIdx.y * gx + blockIdx.x;
  int xcd = id & 7;
  int j = id >> 3;
  int mrows = gridDim.y >> 3;           // m-rows per XCD (gy/8)
  int m0 = (xcd * mrows + j / gx) * 128;
  int n0 = (j % gx) * 128;

  f32x4 acc[4][4] = {};

  // coalesced staging with chunk-XOR pre-swizzled source
  int srow8 = lane >> 3;                    // row within 8-row group (= row&7)
  int scol = ((lane & 7) ^ srow8) * 8;      // pre-swizzled source column
  const ushort* Ab = A + (size_t)(m0 + w * 32 + srow8) * lda + scol;
  const ushort* Bb = B + (size_t)(n0 + w * 32 + srow8) * ldb + scol;
  ushort* AsW = As + (w * 32) * 64;
  ushort* BsW = Bs + (w * 32) * 64;

  for (int k0 = 0; k0 < K; k0 += 64) {
#pragma unroll
    for (int i = 0; i < 4; ++i) {
      gll16(Ab + (size_t)i * 8 * lda + k0, AsW + i * 8 * 64);
      gll16(Bb + (size_t)i * 8 * ldb + k0, BsW + i * 8 * 64);
    }
    __syncthreads();
#pragma unroll
    for (int kk = 0; kk < 2; ++kk) {
      short8 af[4], bf4[4];
#pragma unroll
      for (int mi = 0; mi < 4; ++mi)
        af[mi] = *(const short8*)(&As[(wr * 64 + mi * 16 + c) * 64 + (((kk * 4 + g) ^ (c & 7))) * 8]);
#pragma unroll
      for (int ni = 0; ni < 4; ++ni)
        bf4[ni] = *(const short8*)(&Bs[(wc * 64 + ni * 16 + c) * 64 + (((kk * 4 + g) ^ (c & 7))) * 8]);
#pragma unroll
      for (int mi = 0; mi < 4; ++mi)
#pragma unroll
        for (int ni = 0; ni < 4; ++ni)
          acc[mi][ni] = MFMA_BF16(af[mi], bf4[ni], acc[mi][ni], 0, 0, 0);
    }
    __syncthreads();
  }

  // ---- epilogue: per-wave LDS transpose -> vectorized stores ----
  float* eps = (float*)smem;
  float* my = eps + w * (16 * 68);
  int erow = lane >> 2;          // 0..15
  int ecl = (lane & 3) * 16;     // 0,16,32,48
#pragma unroll
  for (int mi = 0; mi < 4; ++mi) {
#pragma unroll
    for (int ni = 0; ni < 4; ++ni)
#pragma unroll
      for (int r = 0; r < 4; ++r)
        my[(g * 4 + r) * 68 + ni * 16 + c] = acc[mi][ni][r];
    int grow = m0 + wr * 64 + mi * 16 + erow;
    int gcol = n0 + wc * 64 + ecl;
    float4 t0 = *(float4*)(&my[erow * 68 + ecl + 0]);
    float4 t1 = *(float4*)(&my[erow * 68 + ecl + 4]);
    float4 t2 = *(float4*)(&my[erow * 68 + ecl + 8]);
    float4 t3 = *(float4*)(&my[erow * 68 + ecl + 12]);
    size_t off = (size_t)grow * ldc + gcol;
    if (MODE == 1) {
      float4 r0 = *(const float4*)(resid + off + 0);
      float4 r1 = *(const float4*)(resid + off + 4);
      float4 r2 = *(const float4*)(resid + off + 8);
      float4 r3 = *(const float4*)(resid + off + 12);
      t0.x += r0.x; t0.y += r0.y; t0.z += r0.z; t0.w += r0.w;
      t1.x += r1.x; t1.y += r1.y; t1.z += r1.z; t1.w += r1.w;
      t2.x += r2.x; t2.y += r2.y; t2.z += r2.z; t2.w += r2.w;
      t3.x += r3.x; t3.y += r3.y; t3.z += r3.z; t3.w += r3.w;
      *(float4*)(Cf + off + 0) = t0;
      *(float4*)(Cf + off + 4) = t1;
      *(float4*)(Cf + off + 8) = t2;
      *(float4*)(Cf + off + 12) = t3;
    } else if (MODE == 0) {
      uint4 u0, u1;
      u0.x = pack2(t0.x, t0.y); u0.y = pack2(t0.z, t0.w);
      u0.z = pack2(t1.x, t1.y); u0.w = pack2(t1.z, t1.w);
      u1.x = pack2(t2.x, t2.y); u1.y = pack2(t2.z, t2.w);
      u1.z = pack2(t3.x, t3.y); u1.w = pack2(t3.z, t3.w);
      *(uint4*)(Cb + off) = u0;
      *(uint4*)(Cb + off + 8) = u1;
    } else {
      uint4 g0 = *(const uint4*)(Cb + off);
      uint4 g1 = *(const uint4*)(Cb + off + 8);
      uint gw[8] = {g0.x, g0.y, g0.z, g0.w, g1.x, g1.y, g1.z, g1.w};
      float tv[16] = {t0.x, t0.y, t0.z, t0.w, t1.x, t1.y, t1.z, t1.w,
                      t2.x, t2.y, t2.z, t2.w, t3.x, t3.y, t3.z, t3.w};
      float ov[16];
#pragma unroll
      for (int j2 = 0; j2 < 8; ++j2) {
        float ga = bf2f((ushort)(gw[j2] & 0xffff));
        float gb = bf2f((ushort)(gw[j2] >> 16));
        ov[2 * j2]     = ga / (1.f + __expf(-ga)) * tv[2 * j2];
        ov[2 * j2 + 1] = gb / (1.f + __expf(-gb)) * tv[2 * j2 + 1];
      }
      uint4 u0, u1;
      u0.x = pack2(ov[0], ov[1]);   u0.y = pack2(ov[2], ov[3]);
      u0.z = pack2(ov[4], ov[5]);   u0.w = pack2(ov[6], ov[7]);
      u1.x = pack2(ov[8], ov[9]);   u1.y = pack2(ov[10], ov[11]);
      u1.z = pack2(ov[12], ov[13]); u1.w = pack2(ov[14], ov[15]);
      *(uint4*)(Cb + off) = u0;
      *(uint4*)(Cb + off + 8) = u1;
    }
  }
}

// ---------------------------------------------------------------------------
// Per-head RMSNorm + mRoPE, in-place on qkv [4096][5120] bf16.
// ---------------------------------------------------------------------------
__global__ __launch_bounds__(256) void qk_rope_k(ushort* __restrict__ qkv,
                                                 const float* __restrict__ qw, const float* __restrict__ kw,
                                                 const float* __restrict__ cost, const float* __restrict__ sint) {
  int row = blockIdx.x;
  int s = row & 2047;
  int w = threadIdx.x >> 6, l = threadIdx.x & 63;
  ushort* rp = qkv + (size_t)row * 5120;
  float c0 = cost[s * 128 + l], c1 = cost[s * 128 + l + 64];
  float s0 = sint[s * 128 + l], s1 = sint[s * 128 + l + 64];
  float qw0 = qw[l], qw1 = qw[l + 64];
  float kw0 = kw[l], kw1 = kw[l + 64];
#pragma unroll
  for (int i = 0; i < 9; ++i) {
    int hd = w + 4 * i;  // 0..35
    bool isq = hd < 32;
    int colbase = isq ? hd * 128 : 4096 + (hd - 32) * 128;
    ushort* p = rp + colbase;
    float x0 = bf2f(p[l]), x1 = bf2f(p[l + 64]);
    float ss = x0 * x0 + x1 * x1;
#pragma unroll
    for (int msk = 1; msk <= 32; msk <<= 1) ss += __shfl_xor(ss, msk);
    float r = rsqrtf(ss * (1.f / 128.f) + 1e-6f);
    float xn0 = x0 * r * (isq ? qw0 : kw0);
    float xn1 = x1 * r * (isq ? qw1 : kw1);
    float v0 = xn0 * c0 - xn1 * s0;
    float v1 = xn1 * c1 + xn0 * s1;
    if (isq) { v0 *= 0.08838834764831843f; v1 *= 0.08838834764831843f; }
    p[l] = f2bf(v0);
    p[l + 64] = f2bf(v1);
  }
}

// ---------------------------------------------------------------------------
// V transpose via LDS tile: qkv v-cols -> vT[(b*4+kvh)][128][2048]
// ---------------------------------------------------------------------------
__global__ __launch_bounds__(256) void transpose_v_k(const ushort* __restrict__ qkv, ushort* __restrict__ vT) {
  __shared__ ushort Ls[128 * 72];  // [d][s_local], pad 72
  int st = blockIdx.x, kvh = blockIdx.y, b = blockIdx.z;
  int t = threadIdx.x;
  int s0 = st * 64;
  const ushort* src = qkv + (size_t)(b * 2048) * 5120 + 4608 + kvh * 128;
#pragma unroll
  for (int i = 0; i < 4; ++i) {
    int sl = i * 16 + (t >> 4);
    int d0 = (t & 15) * 8;
    short8 v = *(const short8*)(src + (size_t)(s0 + sl) * 5120 + d0);
#pragma unroll
    for (int j = 0; j < 8; ++j) Ls[(d0 + j) * 72 + sl] = (ushort)v[j];
  }
  __syncthreads();
  int d = t >> 1, half = t & 1;
  ushort* dst = vT + (size_t)(b * 4 + kvh) * 128 * 2048 + (size_t)d * 2048 + s0 + half * 32;
#pragma unroll
  for (int j = 0; j < 4; ++j)
    *(uint4*)(dst + j * 8) = *(uint4*)(&Ls[d * 72 + half * 32 + j * 8]);
}

// ---------------------------------------------------------------------------
// Causal GQA flash attention v6: fragment-ordered LDS + dbuf counted vmcnt(8)
// + 2 heads/block + folded causal pairing + maskless interior + defer-max.
// ---------------------------------------------------------------------------
__global__ __launch_bounds__(256, 2) void attn_k(const ushort* __restrict__ qkv,
                                                 const ushort* __restrict__ vT,
                                                 ushort* __restrict__ outp) {
  __shared__ ushort Ks[2][16 * 512];   // 32 KB, subtile (kk*4+f), frag-ordered
  __shared__ ushort Vs[2][16 * 512];   // 32 KB, subtile (kk*8+db)
  __shared__ ushort Ps[4][2][1024];    // 16 KB, per-wave per-head P tile

  int hp = blockIdx.y, b = blockIdx.z;
  int h0 = hp * 2;           // heads h0, h0+1 share kvh
  int kvh = h0 >> 3;
  int tid = threadIdx.x, w = tid >> 6, l = tid & 63, g = l >> 4, c = l & 15;

  const ushort* kbase = qkv + (size_t)(b * 2048) * 5120 + 4096 + kvh * 128;
  const ushort* vbase = vT + (size_t)(b * 4 + kvh) * 128 * 2048;

  int krow = l & 15, kcol = (l >> 4) * 8;  // per-lane fragment source coords

  auto stage = [&](int t, int buf) {
    int kv0 = t * 64;
#pragma unroll
    for (int kk = 0; kk < 4; ++kk)  // K: wave w stages f=w
      gll16(kbase + (size_t)(kv0 + w * 16 + krow) * 5120 + kk * 32 + kcol,
            &Ks[buf][(kk * 4 + w) * 512]);
#pragma unroll
    for (int i = 0; i < 4; ++i) {   // V: wave w stages db=2w,2w+1 for kk=0,1
      int kk = i >> 1, db = 2 * w + (i & 1);
      gll16(vbase + (size_t)(db * 16 + krow) * 2048 + kv0 + kk * 32 + kcol,
            &Vs[buf][(kk * 8 + db) * 512]);
    }
  };

  // two passes: long q-tile (31-bidx) then short (bidx); total 33 tiles/block
#pragma unroll 1
  for (int pass = 0; pass < 2; ++pass) {
    int qt = pass == 0 ? (31 - (int)blockIdx.x) : (int)blockIdx.x;
    int qrow = qt * 64 + w * 16 + c;

    short8 qf0[4], qf1[4];
    const ushort* qp = qkv + (size_t)(b * 2048 + qrow) * 5120 + h0 * 128 + g * 8;
#pragma unroll
    for (int kk = 0; kk < 4; ++kk) {
      qf0[kk] = *(const short8*)(qp + kk * 32);
      qf1[kk] = *(const short8*)(qp + 128 + kk * 32);
    }

    f32x4 o0[8] = {}, o1[8] = {};
    float rmax0 = -1e30f, lsum0 = 0.f, rmax1 = -1e30f, lsum1 = 0.f;

    // returns alpha (1.0f when rescale deferred)
    auto do_softmax = [&](f32x4 sfr[4], float& rmax, float& lsum, ushort* pdst,
                          int kv0, bool need_mask) {
      float sv[16];
      float tmax = -3e38f;
#pragma unroll
      for (int f = 0; f < 4; ++f)
#pragma unroll
        for (int r = 0; r < 4; ++r) {
          int key = kv0 + f * 16 + g * 4 + r;
          float xv = sfr[f][r];
          if (need_mask) xv += (key > qrow) ? -1e9f : 0.f;
          sv[f * 4 + r] = xv;
          tmax = fmaxf(tmax, xv);
        }
      tmax = fmaxf(tmax, __shfl_xor(tmax, 16));
      tmax = fmaxf(tmax, __shfl_xor(tmax, 32));
      float mnew, alpha;
      if (__all(tmax - rmax <= 8.0f)) {   // defer-max: keep old max, no rescale
        mnew = rmax;
        alpha = 1.0f;
      } else {
        mnew = fmaxf(rmax, tmax);
        alpha = __expf(rmax - mnew);
      }
      float psum = 0.f;
      uint pw[8];
#pragma unroll
      for (int i = 0; i < 16; i += 2) {
        float p0 = __expf(sv[i] - mnew);
        float p1 = __expf(sv[i + 1] - mnew);
        psum += p0 + p1;
        pw[i >> 1] = pack2(p0, p1);
      }
      psum += __shfl_xor(psum, 16);
      psum += __shfl_xor(psum, 32);
      lsum = lsum * alpha + psum;
      rmax = mnew;
#pragma unroll
      for (int f = 0; f < 4; ++f)
        *(uint2*)(pdst + (f >> 1) * 512 + (c + 16 * ((f & 1) * 2 + (g >> 1))) * 8 + (g & 1) * 4) =
            make_uint2(pw[2 * f], pw[2 * f + 1]);
      return alpha;
    };

    int nt = qt + 1;
    stage(0, 0);
    for (int t = 0; t < nt; ++t) {
      int cur = t & 1;
      int kv0 = t * 64;
      if (t + 1 < nt) {
        stage(t + 1, cur ^ 1);
        asm volatile("s_waitcnt vmcnt(8)" ::: "memory");
      } else {
        asm volatile("s_waitcnt vmcnt(0)" ::: "memory");
      }
      __builtin_amdgcn_sched_barrier(0);
      __builtin_amdgcn_s_barrier();

      f32x4 s0[4] = {}, s1[4] = {};
      __builtin_amdgcn_s_setprio(1);
#pragma unroll
      for (int kk = 0; kk < 4; ++kk)
#pragma unroll
        for (int f = 0; f < 4; ++f) {
          short8 kf = *(const short8*)(&Ks[cur][(kk * 4 + f) * 512 + l * 8]);
          s0[f] = MFMA_BF16(kf, qf0[kk], s0[f], 0, 0, 0);
          s1[f] = MFMA_BF16(kf, qf1[kk], s1[f], 0, 0, 0);
        }
      __builtin_amdgcn_s_setprio(0);

      bool need_mask = (t == qt);  // only the diagonal tile is masked
      float alpha0 = do_softmax(s0, rmax0, lsum0, &Ps[w][0][0], kv0, need_mask);
      float alpha1 = do_softmax(s1, rmax1, lsum1, &Ps[w][1][0], kv0, need_mask);

      if (alpha0 != 1.0f || alpha1 != 1.0f) {
#pragma unroll
        for (int db = 0; db < 8; ++db) {
          o0[db][0] *= alpha0; o0[db][1] *= alpha0; o0[db][2] *= alpha0; o0[db][3] *= alpha0;
          o1[db][0] *= alpha1; o1[db][1] *= alpha1; o1[db][2] *= alpha1; o1[db][3] *= alpha1;
        }
      }

      __builtin_amdgcn_s_setprio(1);
#pragma unroll
      for (int kk = 0; kk < 2; ++kk) {
        short8 pf0 = *(const short8*)(&Ps[w][0][kk * 512 + l * 8]);
        short8 pf1 = *(const short8*)(&Ps[w][1][kk * 512 + l * 8]);
#pragma unroll
        for (int db = 0; db < 8; ++db) {
          short8 vf = *(const short8*)(&Vs[cur][(kk * 8 + db) * 512 + l * 8]);
          o0[db] = MFMA_BF16(vf, pf0, o0[db], 0, 0, 0);
          o1[db] = MFMA_BF16(vf, pf1, o1[db], 0, 0, 0);
        }
      }
      __builtin_amdgcn_s_setprio(0);
      __builtin_amdgcn_s_barrier();  // all waves done reading before restage
    }

    float inv0 = 1.0f / lsum0, inv1 = 1.0f / lsum1;
    size_t rowoff = (size_t)(b * 2048 + qrow) * 4096 + h0 * 128;
#pragma unroll
    for (int db = 0; db < 8; ++db) {
      *(uint2*)(outp + rowoff + db * 16 + g * 4) =
          make_uint2(pack2(o0[db][0] * inv0, o0[db][1] * inv0), pack2(o0[db][2] * inv0, o0[db][3] * inv0));
      *(uint2*)(outp + rowoff + 128 + db * 16 + g * 4) =
          make_uint2(pack2(o1[db][0] * inv1, o1[db][1] * inv1), pack2(o1[db][2] * inv1, o1[db][3] * inv1));
    }
  }
}

// ---------------------------------------------------------------------------
extern "C" void kernel_launch(void* const* d_in, const int* in_sizes, int n_in,
                              void* d_out, int out_size, void* d_ws, size_t ws_size,
                              hipStream_t stream) {
  const float* x   = (const float*)d_in[0];
  const float* wq  = (const float*)d_in[2];
  const float* wk  = (const float*)d_in[3];
  const float* wv  = (const float*)d_in[4];
  const float* wo  = (const float*)d_in[5];
  const float* qnw = (const float*)d_in[6];
  const float* knw = (const float*)d_in[7];
  const float* ln1 = (const float*)d_in[8];
  const float* ln2 = (const float*)d_in[9];
  const float* wg  = (const float*)d_in[10];
  const float* wu  = (const float*)d_in[11];
  const float* wd  = (const float*)d_in[12];
  float* outp = (float*)d_out;  // also used as hbuf (post-attn residual, fp32)

  char* ws = (char*)d_ws;
  ushort* wqkv_bf = (ushort*)ws; ws += (size_t)5120 * 2048 * 2;
  ushort* wo_bf   = (ushort*)ws; ws += (size_t)2048 * 4096 * 2;
  ushort* wg_bf   = (ushort*)ws; ws += (size_t)8192 * 2048 * 2;
  ushort* wu_bf   = (ushort*)ws; ws += (size_t)8192 * 2048 * 2;
  ushort* wd_bf   = (ushort*)ws; ws += (size_t)2048 * 8192 * 2;
  float*  cost    = (float*)ws;  ws += (size_t)2048 * 128 * 4;
  float*  sint    = (float*)ws;  ws += (size_t)2048 * 128 * 4;
  ushort* h1      = (ushort*)ws; ws += (size_t)4096 * 2048 * 2;
  ushort* h2      = h1;
  ushort* qkv     = (ushort*)ws;
  ushort* vT      = qkv + (size_t)4096 * 5120;
  ushort* atn     = vT + (size_t)8 * 128 * 2048;
  ushort* gate    = qkv;  // qkv/vT/atn dead before FF gemms

  cast_bf16_k<<<4096, 256, 0, stream>>>(wq, wqkv_bf);
  cast_bf16_k<<<512,  256, 0, stream>>>(wk, wqkv_bf + (size_t)4096 * 2048);
  cast_bf16_k<<<512,  256, 0, stream>>>(wv, wqkv_bf + (size_t)4608 * 2048);
  cast_bf16_k<<<4096, 256, 0, stream>>>(wo, wo_bf);
  cast_bf16_k<<<8192, 256, 0, stream>>>(wg, wg_bf);
  cast_bf16_k<<<8192, 256, 0, stream>>>(wu, wu_bf);
  cast_bf16_k<<<8192, 256, 0, stream>>>(wd, wd_bf);

  rope_table_k<<<1024, 256, 0, stream>>>(cost, sint);
  rmsnorm_k<<<4096, 256, 0, stream>>>(x, ln1, h1);

  // fused QKV projection (column-sync XCD map; gy=32)
  gemm_bb<0><<<dim3(40, 32), 256, 0, stream>>>(h1, 2048, wqkv_bf, 2048, qkv, nullptr, nullptr, 5120, 2048);

  qk_rope_k<<<4096, 256, 0, stream>>>(qkv, qnw, knw, cost, sint);
  transpose_v_k<<<dim3(32, 4, 2), 256, 0, stream>>>(qkv, vT);
  // folded causal pairing: grid (16,16,2), uniform 33 tiles/block
  attn_k<<<dim3(16, 16, 2), 256, 0, stream>>>(qkv, vT, atn);

  // O-proj + residual
  gemm_bb<1><<<dim3(16, 32), 256, 0, stream>>>(atn, 4096, wo_bf, 4096, nullptr, outp, x, 2048, 4096);

  rmsnorm_k<<<4096, 256, 0, stream>>>(outp, ln2, h2);
  // gate / up (fused silu*gate)
  gemm_bb<0><<<dim3(64, 32), 256, 0, stream>>>(h2, 2048, wg_bf, 2048, gate, nullptr, nullptr, 8192, 2048);
  gemm_bb<2><<<dim3(64, 32), 256, 0, stream>>>(h2, 2048, wu_bf, 2048, gate, nullptr, nullptr, 8192, 2048);
  // down-proj + residual
  gemm_bb<1><<<dim3(16, 32), 256, 0, stream>>>(gate, 8192, wd_bf, 8192, nullptr, outp, outp, 2048, 8192);
}

// Round 20
// 862.381 us; speedup vs baseline: 1.1043x; 1.1043x over previous
//
#include <hip/hip_runtime.h>
#include <hip/hip_bf16.h>

typedef __attribute__((ext_vector_type(4))) float f32x4;
typedef __attribute__((ext_vector_type(8))) short short8;
using uint = unsigned int;
using ushort = unsigned short;

#define DEV __device__ __forceinline__

DEV ushort f2bf(float f) {
  uint u = __builtin_bit_cast(uint, f);
  u = (u + 0x7fffu + ((u >> 16) & 1u)) >> 16;
  return (ushort)u;
}
DEV float bf2f(ushort b) { uint u = ((uint)b) << 16; return __builtin_bit_cast(float, u); }
DEV uint pack2(float lo, float hi) { return (uint)f2bf(lo) | ((uint)f2bf(hi) << 16); }

// async global->LDS, 16B per lane. LDS dest = wave-uniform base + lane*16.
DEV void gll16(const ushort* g, ushort* l) {
  __builtin_amdgcn_global_load_lds((const __attribute__((address_space(1))) void*)g,
                                   (__attribute__((address_space(3))) void*)l, 16, 0, 0);
}

#define MFMA_BF16 __builtin_amdgcn_mfma_f32_16x16x32_bf16

// ---------------------------------------------------------------------------
// fp32 -> bf16 cast (weights), 8 elems/thread
// ---------------------------------------------------------------------------
__global__ __launch_bounds__(256) void cast_bf16_k(const float* __restrict__ src, ushort* __restrict__ dst) {
  size_t i = ((size_t)blockIdx.x * 256 + threadIdx.x) * 8;
  float4 a = *(const float4*)(src + i);
  float4 b = *(const float4*)(src + i + 4);
  uint4 u;
  u.x = pack2(a.x, a.y); u.y = pack2(a.z, a.w);
  u.z = pack2(b.x, b.y); u.w = pack2(b.z, b.w);
  *(uint4*)(dst + i) = u;
}

// ---------------------------------------------------------------------------
// RoPE cos/sin table: [2048][128], sections [48,40,40] (pairs 24/20/20)
// ---------------------------------------------------------------------------
__global__ __launch_bounds__(256) void rope_table_k(float* __restrict__ cost, float* __restrict__ sint) {
  int idx = blockIdx.x * 256 + threadIdx.x;   // 0..262143
  int s = idx >> 7, d = idx & 127;
  const float LN1E6 = 13.815510557964274f;
  float inv;
  if (d < 48)      { int i = d % 24;        inv = expf((float)i * (-2.f / 48.f) * LN1E6); }
  else if (d < 88) { int i = (d - 48) % 20; inv = expf((float)i * (-2.f / 40.f) * LN1E6); }
  else             { int i = (d - 88) % 20; inv = expf((float)i * (-2.f / 40.f) * LN1E6); }
  float ang = (float)s * inv;
  cost[idx] = cosf(ang);
  sint[idx] = sinf(ang);
}

// ---------------------------------------------------------------------------
// Row RMSNorm: in fp32 [R][2048] * w[2048] -> out bf16
// ---------------------------------------------------------------------------
__global__ __launch_bounds__(256) void rmsnorm_k(const float* __restrict__ in, const float* __restrict__ w,
                                                 ushort* __restrict__ out) {
  int row = blockIdx.x;
  const float* x = in + (size_t)row * 2048;
  int base = threadIdx.x * 8;
  float4 a = *(const float4*)(x + base);
  float4 b = *(const float4*)(x + base + 4);
  float ss = a.x*a.x + a.y*a.y + a.z*a.z + a.w*a.w + b.x*b.x + b.y*b.y + b.z*b.z + b.w*b.w;
#pragma unroll
  for (int msk = 1; msk <= 32; msk <<= 1) ss += __shfl_xor(ss, msk);
  __shared__ float red[4];
  if ((threadIdx.x & 63) == 0) red[threadIdx.x >> 6] = ss;
  __syncthreads();
  float tot = red[0] + red[1] + red[2] + red[3];
  float r = rsqrtf(tot * (1.f / 2048.f) + 1e-6f);
  float4 wa = *(const float4*)(w + base);
  float4 wb = *(const float4*)(w + base + 4);
  uint4 u;
  u.x = pack2(a.x * r * wa.x, a.y * r * wa.y);
  u.y = pack2(a.z * r * wa.z, a.w * r * wa.w);
  u.z = pack2(b.x * r * wb.x, b.y * r * wb.y);
  u.w = pack2(b.z * r * wb.z, b.w * r * wb.w);
  *(uint4*)(out + (size_t)row * 2048 + base) = u;
}

// ---------------------------------------------------------------------------
// GEMM v10 (r16/r18 optimum) — 128x128 tile, BK=64, 4 waves, single 32 KB
// buffer + syncthreads pair, coalesced chunk-XOR-swizzled staging (0
// conflicts), SUPER-gated L2 tile ordering (SUPER=1 for K=2048).
// MODE 0: C bf16.  MODE 1: C fp32 = acc + resid.
// ---------------------------------------------------------------------------
template <int MODE, int SUPER>
__global__ __launch_bounds__(256, 4) void gemm_bb(
    const ushort* __restrict__ A, int lda,
    const ushort* __restrict__ B, int ldb,
    ushort* __restrict__ Cb, float* __restrict__ Cf,
    const float* __restrict__ resid, int ldc, int K) {
  __shared__ ushort smem[2 * 128 * 64];  // As | Bs, 32 KB
  ushort* As = smem;
  ushort* Bs = smem + 128 * 64;

  int tid = threadIdx.x;
  int w = tid >> 6, lane = tid & 63, g = lane >> 4, c = lane & 15;
  int wr = w >> 1, wc = w & 1;

  // XCD chunk swizzle; SUPER adds 8x8 supertile decode (n-fast inner)
  int gx = gridDim.x;
  int nwg = gx * gridDim.y;
  int id = blockIdx.y * gx + blockIdx.x;
  int cpx = nwg >> 3;
  int id2 = (id & 7) * cpx + (id >> 3);
  int m0, n0;
  if (SUPER) {
    int sgx = gx >> 3;
    int s = id2 >> 6, w2 = id2 & 63;
    m0 = ((s / sgx) * 8 + (w2 >> 3)) * 128;
    n0 = ((s % sgx) * 8 + (w2 & 7)) * 128;
  } else {
    m0 = (id2 / gx) * 128;
    n0 = (id2 % gx) * 128;
  }

  f32x4 acc[4][4] = {};

  // coalesced staging with chunk-XOR pre-swizzled source
  int srow8 = lane >> 3;                    // row within 8-row group (= row&7)
  int scol = ((lane & 7) ^ srow8) * 8;      // pre-swizzled source column
  const ushort* Ab = A + (size_t)(m0 + w * 32 + srow8) * lda + scol;
  const ushort* Bb = B + (size_t)(n0 + w * 32 + srow8) * ldb + scol;
  ushort* AsW = As + (w * 32) * 64;
  ushort* BsW = Bs + (w * 32) * 64;

  for (int k0 = 0; k0 < K; k0 += 64) {
#pragma unroll
    for (int i = 0; i < 4; ++i) {
      gll16(Ab + (size_t)i * 8 * lda + k0, AsW + i * 8 * 64);
      gll16(Bb + (size_t)i * 8 * ldb + k0, BsW + i * 8 * 64);
    }
    __syncthreads();
#pragma unroll
    for (int kk = 0; kk < 2; ++kk) {
      short8 af[4], bf4[4];
#pragma unroll
      for (int mi = 0; mi < 4; ++mi)
        af[mi] = *(const short8*)(&As[(wr * 64 + mi * 16 + c) * 64 + (((kk * 4 + g) ^ (c & 7))) * 8]);
#pragma unroll
      for (int ni = 0; ni < 4; ++ni)
        bf4[ni] = *(const short8*)(&Bs[(wc * 64 + ni * 16 + c) * 64 + (((kk * 4 + g) ^ (c & 7))) * 8]);
#pragma unroll
      for (int mi = 0; mi < 4; ++mi)
#pragma unroll
        for (int ni = 0; ni < 4; ++ni)
          acc[mi][ni] = MFMA_BF16(af[mi], bf4[ni], acc[mi][ni], 0, 0, 0);
    }
    __syncthreads();
  }

  // ---- epilogue: per-wave LDS transpose -> vectorized stores ----
  float* eps = (float*)smem;
  float* my = eps + w * (16 * 68);
  int erow = lane >> 2;          // 0..15
  int ecl = (lane & 3) * 16;     // 0,16,32,48
#pragma unroll
  for (int mi = 0; mi < 4; ++mi) {
#pragma unroll
    for (int ni = 0; ni < 4; ++ni)
#pragma unroll
      for (int r = 0; r < 4; ++r)
        my[(g * 4 + r) * 68 + ni * 16 + c] = acc[mi][ni][r];
    int grow = m0 + wr * 64 + mi * 16 + erow;
    int gcol = n0 + wc * 64 + ecl;
    float4 t0 = *(float4*)(&my[erow * 68 + ecl + 0]);
    float4 t1 = *(float4*)(&my[erow * 68 + ecl + 4]);
    float4 t2 = *(float4*)(&my[erow * 68 + ecl + 8]);
    float4 t3 = *(float4*)(&my[erow * 68 + ecl + 12]);
    size_t off = (size_t)grow * ldc + gcol;
    if (MODE == 1) {
      float4 r0 = *(const float4*)(resid + off + 0);
      float4 r1 = *(const float4*)(resid + off + 4);
      float4 r2 = *(const float4*)(resid + off + 8);
      float4 r3 = *(const float4*)(resid + off + 12);
      t0.x += r0.x; t0.y += r0.y; t0.z += r0.z; t0.w += r0.w;
      t1.x += r1.x; t1.y += r1.y; t1.z += r1.z; t1.w += r1.w;
      t2.x += r2.x; t2.y += r2.y; t2.z += r2.z; t2.w += r2.w;
      t3.x += r3.x; t3.y += r3.y; t3.z += r3.z; t3.w += r3.w;
      *(float4*)(Cf + off + 0) = t0;
      *(float4*)(Cf + off + 4) = t1;
      *(float4*)(Cf + off + 8) = t2;
      *(float4*)(Cf + off + 12) = t3;
    } else {
      uint4 u0, u1;
      u0.x = pack2(t0.x, t0.y); u0.y = pack2(t0.z, t0.w);
      u0.z = pack2(t1.x, t1.y); u0.w = pack2(t1.z, t1.w);
      u1.x = pack2(t2.x, t2.y); u1.y = pack2(t2.z, t2.w);
      u1.z = pack2(t3.x, t3.y); u1.w = pack2(t3.z, t3.w);
      *(uint4*)(Cb + off) = u0;
      *(uint4*)(Cb + off + 8) = u1;
    }
  }
}

// ---------------------------------------------------------------------------
// Fused gate/up GEMM + SiLU: act[M][N] = silu(A@Wg^T) * (A@Wu^T), bf16 out.
// Block = 128m x 64n of BOTH gate and up; 4 waves 2x2, wave quadrant
// 64m x 32n holding acc_g[4][2] + acc_u[4][2] (64 regs).  Same K-loop
// structure as gemm_bb (single 32 KB buffer: As 16K | Bg 8K | Bu 8K,
// chunk-XOR swizzle, syncthreads pair).  silu(g)*u computed in registers
// in the epilogue -> no gate intermediate (saves 67 MB traffic + a launch).
// SUPER supertile decode with 128x64 tiles (B-set 4 MB, L2-fit).
// ---------------------------------------------------------------------------
__global__ __launch_bounds__(256, 4) void gemm_gu(
    const ushort* __restrict__ A, int lda,
    const ushort* __restrict__ Bg, const ushort* __restrict__ Bu, int ldb,
    ushort* __restrict__ Cb, int ldc, int K) {
  __shared__ ushort smem[2 * 128 * 64];  // As 16K | Bg 8K | Bu 8K (32 KB)
  ushort* As = smem;
  ushort* Bsg = smem + 128 * 64;
  ushort* Bsu = smem + 128 * 64 + 64 * 64;

  int tid = threadIdx.x;
  int w = tid >> 6, lane = tid & 63, g = lane >> 4, c = lane & 15;
  int wr = w >> 1, wc = w & 1;  // wave quadrant: 64m x 32n

  // XCD chunk swizzle + 8x8 supertile decode (tiles are 128m x 64n)
  int gx = gridDim.x;
  int nwg = gx * gridDim.y;
  int id = blockIdx.y * gx + blockIdx.x;
  int cpx = nwg >> 3;
  int id2 = (id & 7) * cpx + (id >> 3);
  int sgx = gx >> 3;
  int s = id2 >> 6, w2 = id2 & 63;
  int m0 = ((s / sgx) * 8 + (w2 >> 3)) * 128;
  int n0 = ((s % sgx) * 8 + (w2 & 7)) * 64;

  f32x4 accg[4][2] = {}, accu[4][2] = {};

  int srow8 = lane >> 3;
  int scol = ((lane & 7) ^ srow8) * 8;
  const ushort* Ab  = A  + (size_t)(m0 + w * 32 + srow8) * lda + scol;  // 4 calls
  const ushort* Bgb = Bg + (size_t)(n0 + w * 16 + srow8) * ldb + scol;  // 2 calls
  const ushort* Bub = Bu + (size_t)(n0 + w * 16 + srow8) * ldb + scol;  // 2 calls
  ushort* AsW  = As  + (w * 32) * 64;
  ushort* BsgW = Bsg + (w * 16) * 64;
  ushort* BsuW = Bsu + (w * 16) * 64;

  for (int k0 = 0; k0 < K; k0 += 64) {
#pragma unroll
    for (int i = 0; i < 4; ++i)
      gll16(Ab + (size_t)i * 8 * lda + k0, AsW + i * 8 * 64);
#pragma unroll
    for (int i = 0; i < 2; ++i) {
      gll16(Bgb + (size_t)i * 8 * ldb + k0, BsgW + i * 8 * 64);
      gll16(Bub + (size_t)i * 8 * ldb + k0, BsuW + i * 8 * 64);
    }
    __syncthreads();
#pragma unroll
    for (int kk = 0; kk < 2; ++kk) {
      int co = (((kk * 4 + g) ^ (c & 7))) * 8;
      short8 af[4], bg2[2], bu2[2];
#pragma unroll
      for (int mi = 0; mi < 4; ++mi)
        af[mi] = *(const short8*)(&As[(wr * 64 + mi * 16 + c) * 64 + co]);
#pragma unroll
      for (int ni = 0; ni < 2; ++ni) {
        bg2[ni] = *(const short8*)(&Bsg[(wc * 32 + ni * 16 + c) * 64 + co]);
        bu2[ni] = *(const short8*)(&Bsu[(wc * 32 + ni * 16 + c) * 64 + co]);
      }
#pragma unroll
      for (int mi = 0; mi < 4; ++mi)
#pragma unroll
        for (int ni = 0; ni < 2; ++ni) {
          accg[mi][ni] = MFMA_BF16(af[mi], bg2[ni], accg[mi][ni], 0, 0, 0);
          accu[mi][ni] = MFMA_BF16(af[mi], bu2[ni], accu[mi][ni], 0, 0, 0);
        }
    }
    __syncthreads();
  }

  // ---- epilogue: silu(g)*u in registers -> per-wave transpose -> stores ----
  float* eps = (float*)smem;
  float* my = eps + w * (16 * 68);  // 16 rows x 32 cols used (68 stride)
  int erow = lane >> 2;             // 0..15
  int ecl = (lane & 3) * 8;         // 0,8,16,24
#pragma unroll
  for (int mi = 0; mi < 4; ++mi) {
#pragma unroll
    for (int ni = 0; ni < 2; ++ni)
#pragma unroll
      for (int r = 0; r < 4; ++r) {
        float gv = accg[mi][ni][r], uv = accu[mi][ni][r];
        my[(g * 4 + r) * 68 + ni * 16 + c] = gv / (1.f + __expf(-gv)) * uv;
      }
    int grow = m0 + wr * 64 + mi * 16 + erow;
    int gcol = n0 + wc * 32 + ecl;
    float4 t0 = *(float4*)(&my[erow * 68 + ecl + 0]);
    float4 t1 = *(float4*)(&my[erow * 68 + ecl + 4]);
    uint4 u;
    u.x = pack2(t0.x, t0.y); u.y = pack2(t0.z, t0.w);
    u.z = pack2(t1.x, t1.y); u.w = pack2(t1.z, t1.w);
    *(uint4*)(Cb + (size_t)grow * ldc + gcol) = u;
  }
}

// ---------------------------------------------------------------------------
// Per-head RMSNorm + mRoPE, in-place on qkv [4096][5120] bf16.
// ---------------------------------------------------------------------------
__global__ __launch_bounds__(256) void qk_rope_k(ushort* __restrict__ qkv,
                                                 const float* __restrict__ qw, const float* __restrict__ kw,
                                                 const float* __restrict__ cost, const float* __restrict__ sint) {
  int row = blockIdx.x;
  int s = row & 2047;
  int w = threadIdx.x >> 6, l = threadIdx.x & 63;
  ushort* rp = qkv + (size_t)row * 5120;
  float c0 = cost[s * 128 + l], c1 = cost[s * 128 + l + 64];
  float s0 = sint[s * 128 + l], s1 = sint[s * 128 + l + 64];
  float qw0 = qw[l], qw1 = qw[l + 64];
  float kw0 = kw[l], kw1 = kw[l + 64];
#pragma unroll
  for (int i = 0; i < 9; ++i) {
    int hd = w + 4 * i;  // 0..35
    bool isq = hd < 32;
    int colbase = isq ? hd * 128 : 4096 + (hd - 32) * 128;
    ushort* p = rp + colbase;
    float x0 = bf2f(p[l]), x1 = bf2f(p[l + 64]);
    float ss = x0 * x0 + x1 * x1;
#pragma unroll
    for (int msk = 1; msk <= 32; msk <<= 1) ss += __shfl_xor(ss, msk);
    float r = rsqrtf(ss * (1.f / 128.f) + 1e-6f);
    float xn0 = x0 * r * (isq ? qw0 : kw0);
    float xn1 = x1 * r * (isq ? qw1 : kw1);
    float v0 = xn0 * c0 - xn1 * s0;
    float v1 = xn1 * c1 + xn0 * s1;
    if (isq) { v0 *= 0.08838834764831843f; v1 *= 0.08838834764831843f; }
    p[l] = f2bf(v0);
    p[l + 64] = f2bf(v1);
  }
}

// ---------------------------------------------------------------------------
// V transpose via LDS tile: qkv v-cols -> vT[(b*4+kvh)][128][2048]
// ---------------------------------------------------------------------------
__global__ __launch_bounds__(256) void transpose_v_k(const ushort* __restrict__ qkv, ushort* __restrict__ vT) {
  __shared__ ushort Ls[128 * 72];  // [d][s_local], pad 72
  int st = blockIdx.x, kvh = blockIdx.y, b = blockIdx.z;
  int t = threadIdx.x;
  int s0 = st * 64;
  const ushort* src = qkv + (size_t)(b * 2048) * 5120 + 4608 + kvh * 128;
#pragma unroll
  for (int i = 0; i < 4; ++i) {
    int sl = i * 16 + (t >> 4);
    int d0 = (t & 15) * 8;
    short8 v = *(const short8*)(src + (size_t)(s0 + sl) * 5120 + d0);
#pragma unroll
    for (int j = 0; j < 8; ++j) Ls[(d0 + j) * 72 + sl] = (ushort)v[j];
  }
  __syncthreads();
  int d = t >> 1, half = t & 1;
  ushort* dst = vT + (size_t)(b * 4 + kvh) * 128 * 2048 + (size_t)d * 2048 + s0 + half * 32;
#pragma unroll
  for (int j = 0; j < 4; ++j)
    *(uint4*)(dst + j * 8) = *(uint4*)(&Ls[d * 72 + half * 32 + j * 8]);
}

// ---------------------------------------------------------------------------
// Causal GQA flash attention v6: fragment-ordered LDS + dbuf counted vmcnt(8)
// + 2 heads/block + folded causal pairing + maskless interior + defer-max.
// ---------------------------------------------------------------------------
__global__ __launch_bounds__(256, 2) void attn_k(const ushort* __restrict__ qkv,
                                                 const ushort* __restrict__ vT,
                                                 ushort* __restrict__ outp) {
  __shared__ ushort Ks[2][16 * 512];   // 32 KB, subtile (kk*4+f), frag-ordered
  __shared__ ushort Vs[2][16 * 512];   // 32 KB, subtile (kk*8+db)
  __shared__ ushort Ps[4][2][1024];    // 16 KB, per-wave per-head P tile

  int hp = blockIdx.y, b = blockIdx.z;
  int h0 = hp * 2;           // heads h0, h0+1 share kvh
  int kvh = h0 >> 3;
  int tid = threadIdx.x, w = tid >> 6, l = tid & 63, g = l >> 4, c = l & 15;

  const ushort* kbase = qkv + (size_t)(b * 2048) * 5120 + 4096 + kvh * 128;
  const ushort* vbase = vT + (size_t)(b * 4 + kvh) * 128 * 2048;

  int krow = l & 15, kcol = (l >> 4) * 8;  // per-lane fragment source coords

  auto stage = [&](int t, int buf) {
    int kv0 = t * 64;
#pragma unroll
    for (int kk = 0; kk < 4; ++kk)  // K: wave w stages f=w
      gll16(kbase + (size_t)(kv0 + w * 16 + krow) * 5120 + kk * 32 + kcol,
            &Ks[buf][(kk * 4 + w) * 512]);
#pragma unroll
    for (int i = 0; i < 4; ++i) {   // V: wave w stages db=2w,2w+1 for kk=0,1
      int kk = i >> 1, db = 2 * w + (i & 1);
      gll16(vbase + (size_t)(db * 16 + krow) * 2048 + kv0 + kk * 32 + kcol,
            &Vs[buf][(kk * 8 + db) * 512]);
    }
  };

  // two passes: long q-tile (31-bidx) then short (bidx); total 33 tiles/block
#pragma unroll 1
  for (int pass = 0; pass < 2; ++pass) {
    int qt = pass == 0 ? (31 - (int)blockIdx.x) : (int)blockIdx.x;
    int qrow = qt * 64 + w * 16 + c;

    short8 qf0[4], qf1[4];
    const ushort* qp = qkv + (size_t)(b * 2048 + qrow) * 5120 + h0 * 128 + g * 8;
#pragma unroll
    for (int kk = 0; kk < 4; ++kk) {
      qf0[kk] = *(const short8*)(qp + kk * 32);
      qf1[kk] = *(const short8*)(qp + 128 + kk * 32);
    }

    f32x4 o0[8] = {}, o1[8] = {};
    float rmax0 = -1e30f, lsum0 = 0.f, rmax1 = -1e30f, lsum1 = 0.f;

    // returns alpha (1.0f when rescale deferred)
    auto do_softmax = [&](f32x4 sfr[4], float& rmax, float& lsum, ushort* pdst,
                          int kv0, bool need_mask) {
      float sv[16];
      float tmax = -3e38f;
#pragma unroll
      for (int f = 0; f < 4; ++f)
#pragma unroll
        for (int r = 0; r < 4; ++r) {
          int key = kv0 + f * 16 + g * 4 + r;
          float xv = sfr[f][r];
          if (need_mask) xv += (key > qrow) ? -1e9f : 0.f;
          sv[f * 4 + r] = xv;
          tmax = fmaxf(tmax, xv);
        }
      tmax = fmaxf(tmax, __shfl_xor(tmax, 16));
      tmax = fmaxf(tmax, __shfl_xor(tmax, 32));
      float mnew, alpha;
      if (__all(tmax - rmax <= 8.0f)) {   // defer-max: keep old max, no rescale
        mnew = rmax;
        alpha = 1.0f;
      } else {
        mnew = fmaxf(rmax, tmax);
        alpha = __expf(rmax - mnew);
      }
      float psum = 0.f;
      uint pw[8];
#pragma unroll
      for (int i = 0; i < 16; i += 2) {
        float p0 = __expf(sv[i] - mnew);
        float p1 = __expf(sv[i + 1] - mnew);
        psum += p0 + p1;
        pw[i >> 1] = pack2(p0, p1);
      }
      psum += __shfl_xor(psum, 16);
      psum += __shfl_xor(psum, 32);
      lsum = lsum * alpha + psum;
      rmax = mnew;
#pragma unroll
      for (int f = 0; f < 4; ++f)
        *(uint2*)(pdst + (f >> 1) * 512 + (c + 16 * ((f & 1) * 2 + (g >> 1))) * 8 + (g & 1) * 4) =
            make_uint2(pw[2 * f], pw[2 * f + 1]);
      return alpha;
    };

    int nt = qt + 1;
    stage(0, 0);
    for (int t = 0; t < nt; ++t) {
      int cur = t & 1;
      int kv0 = t * 64;
      if (t + 1 < nt) {
        stage(t + 1, cur ^ 1);
        asm volatile("s_waitcnt vmcnt(8)" ::: "memory");
      } else {
        asm volatile("s_waitcnt vmcnt(0)" ::: "memory");
      }
      __builtin_amdgcn_sched_barrier(0);
      __builtin_amdgcn_s_barrier();

      f32x4 s0[4] = {}, s1[4] = {};
      __builtin_amdgcn_s_setprio(1);
#pragma unroll
      for (int kk = 0; kk < 4; ++kk)
#pragma unroll
        for (int f = 0; f < 4; ++f) {
          short8 kf = *(const short8*)(&Ks[cur][(kk * 4 + f) * 512 + l * 8]);
          s0[f] = MFMA_BF16(kf, qf0[kk], s0[f], 0, 0, 0);
          s1[f] = MFMA_BF16(kf, qf1[kk], s1[f], 0, 0, 0);
        }
      __builtin_amdgcn_s_setprio(0);

      bool need_mask = (t == qt);  // only the diagonal tile is masked
      float alpha0 = do_softmax(s0, rmax0, lsum0, &Ps[w][0][0], kv0, need_mask);
      float alpha1 = do_softmax(s1, rmax1, lsum1, &Ps[w][1][0], kv0, need_mask);

      if (alpha0 != 1.0f || alpha1 != 1.0f) {
#pragma unroll
        for (int db = 0; db < 8; ++db) {
          o0[db][0] *= alpha0; o0[db][1] *= alpha0; o0[db][2] *= alpha0; o0[db][3] *= alpha0;
          o1[db][0] *= alpha1; o1[db][1] *= alpha1; o1[db][2] *= alpha1; o1[db][3] *= alpha1;
        }
      }

      __builtin_amdgcn_s_setprio(1);
#pragma unroll
      for (int kk = 0; kk < 2; ++kk) {
        short8 pf0 = *(const short8*)(&Ps[w][0][kk * 512 + l * 8]);
        short8 pf1 = *(const short8*)(&Ps[w][1][kk * 512 + l * 8]);
#pragma unroll
        for (int db = 0; db < 8; ++db) {
          short8 vf = *(const short8*)(&Vs[cur][(kk * 8 + db) * 512 + l * 8]);
          o0[db] = MFMA_BF16(vf, pf0, o0[db], 0, 0, 0);
          o1[db] = MFMA_BF16(vf, pf1, o1[db], 0, 0, 0);
        }
      }
      __builtin_amdgcn_s_setprio(0);
      __builtin_amdgcn_s_barrier();  // all waves done reading before restage
    }

    float inv0 = 1.0f / lsum0, inv1 = 1.0f / lsum1;
    size_t rowoff = (size_t)(b * 2048 + qrow) * 4096 + h0 * 128;
#pragma unroll
    for (int db = 0; db < 8; ++db) {
      *(uint2*)(outp + rowoff + db * 16 + g * 4) =
          make_uint2(pack2(o0[db][0] * inv0, o0[db][1] * inv0), pack2(o0[db][2] * inv0, o0[db][3] * inv0));
      *(uint2*)(outp + rowoff + 128 + db * 16 + g * 4) =
          make_uint2(pack2(o1[db][0] * inv1, o1[db][1] * inv1), pack2(o1[db][2] * inv1, o1[db][3] * inv1));
    }
  }
}

// ---------------------------------------------------------------------------
extern "C" void kernel_launch(void* const* d_in, const int* in_sizes, int n_in,
                              void* d_out, int out_size, void* d_ws, size_t ws_size,
                              hipStream_t stream) {
  const float* x   = (const float*)d_in[0];
  const float* wq  = (const float*)d_in[2];
  const float* wk  = (const float*)d_in[3];
  const float* wv  = (const float*)d_in[4];
  const float* wo  = (const float*)d_in[5];
  const float* qnw = (const float*)d_in[6];
  const float* knw = (const float*)d_in[7];
  const float* ln1 = (const float*)d_in[8];
  const float* ln2 = (const float*)d_in[9];
  const float* wg  = (const float*)d_in[10];
  const float* wu  = (const float*)d_in[11];
  const float* wd  = (const float*)d_in[12];
  float* outp = (float*)d_out;  // also used as hbuf (post-attn residual, fp32)

  char* ws = (char*)d_ws;
  ushort* wqkv_bf = (ushort*)ws; ws += (size_t)5120 * 2048 * 2;
  ushort* wo_bf   = (ushort*)ws; ws += (size_t)2048 * 4096 * 2;
  ushort* wg_bf   = (ushort*)ws; ws += (size_t)8192 * 2048 * 2;
  ushort* wu_bf   = (ushort*)ws; ws += (size_t)8192 * 2048 * 2;
  ushort* wd_bf   = (ushort*)ws; ws += (size_t)2048 * 8192 * 2;
  float*  cost    = (float*)ws;  ws += (size_t)2048 * 128 * 4;
  float*  sint    = (float*)ws;  ws += (size_t)2048 * 128 * 4;
  ushort* h1      = (ushort*)ws; ws += (size_t)4096 * 2048 * 2;
  ushort* h2      = h1;
  ushort* qkv     = (ushort*)ws;
  ushort* vT      = qkv + (size_t)4096 * 5120;
  ushort* atn     = vT + (size_t)8 * 128 * 2048;
  ushort* gate    = qkv;  // qkv/vT/atn dead before FF gemms

  cast_bf16_k<<<4096, 256, 0, stream>>>(wq, wqkv_bf);
  cast_bf16_k<<<512,  256, 0, stream>>>(wk, wqkv_bf + (size_t)4096 * 2048);
  cast_bf16_k<<<512,  256, 0, stream>>>(wv, wqkv_bf + (size_t)4608 * 2048);
  cast_bf16_k<<<4096, 256, 0, stream>>>(wo, wo_bf);
  cast_bf16_k<<<8192, 256, 0, stream>>>(wg, wg_bf);
  cast_bf16_k<<<8192, 256, 0, stream>>>(wu, wu_bf);
  cast_bf16_k<<<8192, 256, 0, stream>>>(wd, wd_bf);

  rope_table_k<<<1024, 256, 0, stream>>>(cost, sint);
  rmsnorm_k<<<4096, 256, 0, stream>>>(x, ln1, h1);

  // fused QKV projection: K=2048 -> SUPER=1
  gemm_bb<0, 1><<<dim3(40, 32), 256, 0, stream>>>(h1, 2048, wqkv_bf, 2048, qkv, nullptr, nullptr, 5120, 2048);

  qk_rope_k<<<4096, 256, 0, stream>>>(qkv, qnw, knw, cost, sint);
  transpose_v_k<<<dim3(32, 4, 2), 256, 0, stream>>>(qkv, vT);
  // folded causal pairing: grid (16,16,2), uniform 33 tiles/block
  attn_k<<<dim3(16, 16, 2), 256, 0, stream>>>(qkv, vT, atn);

  // O-proj + residual: K=4096 -> SUPER=0
  gemm_bb<1, 0><<<dim3(16, 32), 256, 0, stream>>>(atn, 4096, wo_bf, 4096, nullptr, outp, x, 2048, 4096);

  rmsnorm_k<<<4096, 256, 0, stream>>>(outp, ln2, h2);
  // FUSED gate/up + SiLU: grid (128,32) = 4096 blocks, 128m x 64n tiles
  gemm_gu<<<dim3(128, 32), 256, 0, stream>>>(h2, 2048, wg_bf, wu_bf, 2048, gate, 8192, 2048);
  // down-proj + residual: K=8192 -> SUPER=0
  gemm_bb<1, 0><<<dim3(16, 32), 256, 0, stream>>>(gate, 8192, wd_bf, 8192, nullptr, outp, outp, 2048, 8192);
}